// Round 3
// baseline (2109.544 us; speedup 1.0000x reference)
//
#include <hip/hip_runtime.h>
#include <hip/hip_bf16.h>

typedef unsigned short u16;
typedef __attribute__((ext_vector_type(8))) short bf16x8;    // 8 bf16 in 4 VGPRs
typedef __attribute__((ext_vector_type(16))) float f32x16;

static __device__ __forceinline__ u16 f2bf(float f) {
    unsigned u = __float_as_uint(f);
    unsigned r = (u + 0x7fffu + ((u >> 16) & 1u)) >> 16;   // RNE
    return (u16)r;
}
static __device__ __forceinline__ float bf2f(u16 u) {
    return __uint_as_float(((unsigned)u) << 16);
}

static __device__ __forceinline__ void async_copy16(const void* gptr, void* lptr) {
    __builtin_amdgcn_global_load_lds(
        (const __attribute__((address_space(1))) void*)gptr,
        (__attribute__((address_space(3))) void*)lptr, 16, 0, 0);
}

// ---------------------------------------------------------------------------
// fp32 -> bf16 for all three inputs in ONE launch.
// ---------------------------------------------------------------------------
__global__ __launch_bounds__(256)
void cvt_all(const float* __restrict__ a, const float* __restrict__ b,
             const float* __restrict__ c,
             u16* __restrict__ oa, u16* __restrict__ ob, u16* __restrict__ oc) {
    int blk = blockIdx.x;
    const float* src; u16* dst; long base;
    if (blk < 16384)      { src = a; dst = oa; base = blk; }
    else if (blk < 28672) { src = b; dst = ob; base = blk - 16384; }
    else                  { src = c; dst = oc; base = blk - 28672; }
    long i = (base * 256 + threadIdx.x) * 4;
    float4 f = *(const float4*)(src + i);
    u16 o[4] = { f2bf(f.x), f2bf(f.y), f2bf(f.z), f2bf(f.w) };
    *(uint2*)(dst + i) = *(const uint2*)o;
}

// ---------------------------------------------------------------------------
// C[m,n] = sum_k A[m,k] * B[n,k]   (row-major, K contiguous — "BT" gemm)
//
// 256x256 tile, BK=64, 512 threads = 8 waves (2M x 4N), wave tile 128x64 as
// 4x2 of mfma_f32_32x32x16_bf16. Two LDS dbufs, 8 phases per 2 K-tiles.
//
// R3: uniform prefetch-one-phase-ahead schedule. Per phase:
//   { 4-or-8 ds_read_b128 (fragments for a LATER phase) || 1 region staged
//     (2 global_load_lds) } -> BAR -> lgkmcnt(R_phase) (leaves THIS phase's
//   reads in flight; prev phase's reads drained UNDER the prev MFMA cluster)
//   -> setprio(1) 8x mfma_32x32x16 setprio(0) -> vmcnt(10) -> BAR.
// Quadrant order per tile: (M0N0),(M0N1),(M1N1),(M1N0); A/B fragment sets
// Aa/Ab/Ba/Bb rotate with period 8 (all live ranges verified disjoint).
//
// LDS geometry = R1's measured-zero-conflict one: regions of 128 phys rows x
// 64 u16 (128B row stride), 16B slot s = kc ^ (p&7) (3-bit XOR). Swizzle is
// pre-applied on the GLOBAL source address at staging (global_load_lds
// demands linear lane*16B dests); fragment reads un-swizzle with same XOR.
// Region map (per dbuf, u16 offsets): A-Mq at q*8192 (phys row p=wm*64+m*32
// +l32 <-> global row wm*128+Mq*64+(m*32+l32)); B-Nq at 16384+q*8192
// (p=wn*32+l32 <-> global col wn*64+Nq*32+l32).
//
// Hazard calendar (all HARD-ordered, no latency races):
//   region read-phase -> re-staged read+2 (reader lgkm-confirms pre-BAR2,
//   stage issues post-BAR2) -> lands by read+8-2 via vmcnt(10)/phase-end
//   (exact fit: stage at ph_x confirmed at end of ph_{x+5}, read ph_{x+6}).
// M,N mult of 256, K mult of 128, gridDim.x mult of 8, K>=256.
// ---------------------------------------------------------------------------
template<bool BF16_OUT>
__global__ __launch_bounds__(512, 2)
void gemm_bt8(const u16* __restrict__ A, const u16* __restrict__ B,
              void* __restrict__ Cout, int M, int N, int K) {
    __shared__ __align__(16) u16 lds[65536];   // 128 KiB = 2 dbufs x (A 16K | B 16K)

    const int t    = threadIdx.x;              // 0..511
    const int lane = t & 63;
    const int wm   = (t >> 6) >> 2;            // 0..1
    const int wn   = (t >> 6) & 3;             // 0..3
    const int l32  = lane & 31;
    const int hi   = lane >> 5;                // 0..1

    // XCD-aware panel remap (bijective since gridDim.x % 8 == 0)
    const int id   = blockIdx.y * gridDim.x + blockIdx.x;
    const int cpx  = gridDim.x >> 3;
    const int bx   = (id & 7) * cpx + ((id >> 3) % cpx);
    const int by   = (id >> 3) / cpx;
    const long rowA = (long)by * 256;
    const long rowB = (long)bx * 256;

    // ---- staging sources (pre-swizzled global addresses) ----
    // copy j of a region: phys row p = j*64 + (t>>3), slot = t&7,
    // logical chunk kc = slot ^ (p&7)  [(p&7) == ((t>>3)&7) for both j]
    const int tr  = t >> 3;                    // 0..63
    const int kcs = ((t & 7) ^ (tr & 7)) * 8;
    const u16* A0s = A + (rowA + tr) * (long)K + kcs;                       // j=0
    const u16* B0s = B + (rowB + (tr >> 5) * 64 + (tr & 31)) * (long)K + kcs;
    const long dK128 = 128 * (long)K;          // j=1 source = j=0 + 128 rows
    const long aQ = 64 * (long)K;              // A region q=1 source offset
    const long bQ = 32 * (long)K;              // B region q=1 source offset
    const int t8 = t * 8;

    auto STAGE_A = [&](int dbuf, int q, int kk) {
        const u16* s = A0s + (q ? aQ : 0) + kk;
        u16* d = lds + dbuf + q * 8192 + t8;
        async_copy16(s, d);
        async_copy16(s + dK128, d + 4096);
    };
    auto STAGE_B = [&](int dbuf, int q, int kk) {
        const u16* s = B0s + (q ? bQ : 0) + kk;
        u16* d = lds + dbuf + 16384 + q * 8192 + t8;
        async_copy16(s, d);
        async_copy16(s + dK128, d + 4096);
    };

    // ---- fragment read offsets (u16 units) ----
    // addr = dbuf + region + p*64 + ((kc ^ (p&7))*8); kc = ks*2 + hi;
    // (kc^(p&7))*8 == (ks*16 + hi*8) ^ ((lane&7)*8)  [disjoint-bit XOR]
    const int xo   = (lane & 7) * 8;
    const int hi8  = hi * 8;
    const int aRow = (wm * 64 + l32) * 64;     // + m*2048
    const int bRow = (wn * 32 + l32) * 64;

    bf16x8 Aa[2][4], Ab[2][4], Ba[4], Bb[4];
    f32x16 acc[4][2] = {};

    auto LOAD_A = [&](bf16x8 (&as)[2][4], int dbuf, int q) {
#pragma unroll
        for (int m = 0; m < 2; m++) {
            const u16* base = lds + dbuf + q * 8192 + aRow + m * 2048;
#pragma unroll
            for (int ks = 0; ks < 4; ks++)
                as[m][ks] = *(const bf16x8*)(base + ((ks * 16 + hi8) ^ xo));
        }
    };
    auto LOAD_B = [&](bf16x8 (&bs)[4], int dbuf, int q) {
        const u16* base = lds + dbuf + 16384 + q * 8192 + bRow;
#pragma unroll
        for (int ks = 0; ks < 4; ks++)
            bs[ks] = *(const bf16x8*)(base + ((ks * 16 + hi8) ^ xo));
    };

#define MFMA_Q(MQ, NQ, AS, BS) do {                                          \
    __builtin_amdgcn_s_setprio(1);                                           \
    _Pragma("unroll")                                                        \
    for (int ks = 0; ks < 4; ks++) {                                         \
        acc[(MQ)*2+0][NQ] = __builtin_amdgcn_mfma_f32_32x32x16_bf16(         \
            AS[0][ks], BS[ks], acc[(MQ)*2+0][NQ], 0, 0, 0);                  \
        acc[(MQ)*2+1][NQ] = __builtin_amdgcn_mfma_f32_32x32x16_bf16(         \
            AS[1][ks], BS[ks], acc[(MQ)*2+1][NQ], 0, 0, 0);                  \
    }                                                                        \
    __builtin_amdgcn_s_setprio(0);                                           \
} while (0)

#define BAR()   __builtin_amdgcn_s_barrier()
#define SB()    __builtin_amdgcn_sched_barrier(0)
#define LGKM(N) asm volatile("s_waitcnt lgkmcnt(" #N ")" ::: "memory")
#define VM10()  asm volatile("s_waitcnt vmcnt(10)" ::: "memory")

    // ---- prologue: tile0 -> buf0, tile1 -> buf1; preload Aa/Ba ----
    STAGE_A(0, 0, 0);      STAGE_A(0, 1, 0);
    STAGE_B(0, 0, 0);      STAGE_B(0, 1, 0);
    STAGE_A(32768, 0, 64); STAGE_A(32768, 1, 64);
    STAGE_B(32768, 0, 64); STAGE_B(32768, 1, 64);
    asm volatile("s_waitcnt vmcnt(0)" ::: "memory");
    BAR();
    LOAD_A(Aa, 0, 0);      LOAD_B(Ba, 0, 0);
    LGKM(0);               // hard-order: prologue reads done before ph1 stage
    BAR();

    const int NI = K >> 7;                     // 2 K-tiles per iter
#pragma unroll 1
    for (int i = 0; i < NI; i++) {
        int kT2 = (i << 7) + 128; if (kT2 >= K) kT2 -= K;  // tail: junk,
        int kT3 = (i << 7) + 192; if (kT3 >= K) kT3 -= K;  //  never consumed
        // ph1: Q(T,M0N0); prefetch B(T)N1; stage A(T+2)M0 [read prev-ph7]
        LOAD_B(Bb, 0, 1);      STAGE_A(0, 0, kT2);
        BAR(); LGKM(4); SB();  MFMA_Q(0, 0, Aa, Ba);  VM10(); BAR();
        // ph2: Q(T,M0N1); prefetch A(T)M1; stage B(T+2)N0 [read prev-ph8]
        LOAD_A(Ab, 0, 1);      STAGE_B(0, 0, kT2);
        BAR(); LGKM(8); SB();  MFMA_Q(0, 1, Aa, Bb);  VM10(); BAR();
        // ph3: Q(T,M1N1); prefetch A(T+1)M0; stage B(T+2)N1 [read ph1]
        LOAD_A(Aa, 32768, 0);  STAGE_B(0, 1, kT2);
        BAR(); LGKM(8); SB();  MFMA_Q(1, 1, Ab, Bb);  VM10(); BAR();
        // ph4: Q(T,M1N0); prefetch B(T+1)N0; stage A(T+2)M1 [read ph2]
        LOAD_B(Bb, 32768, 0);  STAGE_A(0, 1, kT2);
        BAR(); LGKM(4); SB();  MFMA_Q(1, 0, Ab, Ba);  VM10(); BAR();
        // ph5: Q(T+1,M0N0); prefetch B(T+1)N1; stage A(T+3)M0 [read ph3]
        LOAD_B(Ba, 32768, 1);  STAGE_A(32768, 0, kT3);
        BAR(); LGKM(4); SB();  MFMA_Q(0, 0, Aa, Bb);  VM10(); BAR();
        // ph6: Q(T+1,M0N1); prefetch A(T+1)M1; stage B(T+3)N0 [read ph4]
        LOAD_A(Ab, 32768, 1);  STAGE_B(32768, 0, kT3);
        BAR(); LGKM(8); SB();  MFMA_Q(0, 1, Aa, Ba);  VM10(); BAR();
        // ph7: Q(T+1,M1N1); prefetch A(T+2)M0; stage B(T+3)N1 [read ph5]
        LOAD_A(Aa, 0, 0);      STAGE_B(32768, 1, kT3);
        BAR(); LGKM(8); SB();  MFMA_Q(1, 1, Ab, Ba);  VM10(); BAR();
        // ph8: Q(T+1,M1N0); prefetch B(T+2)N0; stage A(T+3)M1 [read ph6]
        LOAD_B(Ba, 0, 0);      STAGE_A(32768, 1, kT3);
        BAR(); LGKM(4); SB();  MFMA_Q(1, 0, Ab, Bb);  VM10(); BAR();
    }
    // drain in-flight LDS-targeted loads / reads before LDS dealloc
    asm volatile("s_waitcnt vmcnt(0) lgkmcnt(0)" ::: "memory");

#undef MFMA_Q
#undef BAR
#undef SB
#undef LGKM
#undef VM10

    // ---- epilogue: 32x32 C/D layout col=lane&31, row=(r&3)+8*(r>>2)+4*hi ----
#pragma unroll
    for (int mi = 0; mi < 4; mi++) {
#pragma unroll
        for (int nj = 0; nj < 2; nj++) {
#pragma unroll
            for (int r = 0; r < 16; r++) {
                int rowt = (r & 3) + 8 * (r >> 2) + 4 * hi;
                long m = rowA + wm * 128 + mi * 32 + rowt;
                long n = rowB + wn * 64 + nj * 32 + l32;
                float v = acc[mi][nj][r];
                if (BF16_OUT) ((u16*)Cout)[m * N + n] = f2bf(v);
                else          ((float*)Cout)[m * N + n] = v;
            }
        }
    }
}

// ---------------------------------------------------------------------------
// Fused Bx-product + depthwise causal conv(L=3) + C-gate.
// BCx: (8192, 6144) bf16 rows = [B(0:2048) | C(2048:4096) | x(4096:6144)]
// y[s,h] = C[s,h] * ( w[h,0]*Bx[s-2,h] + w[h,1]*Bx[s-1,h] + w[h,2]*Bx[s,h] )
// batch boundary: s resets every 4096 rows (zero left-pad per batch)
// ---------------------------------------------------------------------------
union U16x8 { uint4 v; u16 u[8]; };

__global__ __launch_bounds__(256)
void conv_fuse(const u16* __restrict__ BCx, const float* __restrict__ cw,
               u16* __restrict__ y) {
    const int row = blockIdx.x;            // 0..8191
    const int h0  = threadIdx.x * 8;       // 256*8 = 2048
    const int sl  = row & 4095;
    const u16* r0 = BCx + (long)row * 6144;

    U16x8 B0, X0, C0, B1, X1, B2, X2;
    B0.v = *(const uint4*)(r0 + h0);
    C0.v = *(const uint4*)(r0 + 2048 + h0);
    X0.v = *(const uint4*)(r0 + 4096 + h0);
    if (sl >= 1) {
        B1.v = *(const uint4*)(r0 - 6144 + h0);
        X1.v = *(const uint4*)(r0 - 6144 + 4096 + h0);
    } else { B1.v = make_uint4(0,0,0,0); X1.v = make_uint4(0,0,0,0); }
    if (sl >= 2) {
        B2.v = *(const uint4*)(r0 - 12288 + h0);
        X2.v = *(const uint4*)(r0 - 12288 + 4096 + h0);
    } else { B2.v = make_uint4(0,0,0,0); X2.v = make_uint4(0,0,0,0); }

    U16x8 o;
#pragma unroll
    for (int i = 0; i < 8; i++) {
        int h = h0 + i;
        float bx0 = bf2f(B0.u[i]) * bf2f(X0.u[i]);   // tap l=2 (current)
        float bx1 = bf2f(B1.u[i]) * bf2f(X1.u[i]);   // tap l=1 (s-1)
        float bx2 = bf2f(B2.u[i]) * bf2f(X2.u[i]);   // tap l=0 (s-2)
        float v = cw[h*3+2] * bx0 + cw[h*3+1] * bx1 + cw[h*3] * bx2;
        o.u[i] = f2bf(v * bf2f(C0.u[i]));
    }
    *(uint4*)(y + (long)row * 2048 + h0) = o.v;
}

// ---------------------------------------------------------------------------
extern "C" void kernel_launch(void* const* d_in, const int* in_sizes, int n_in,
                              void* d_out, int out_size, void* d_ws, size_t ws_size,
                              hipStream_t stream) {
    const float* hs   = (const float*)d_in[0];   // (2,4096,2048)
    const float* Win  = (const float*)d_in[1];   // (6144,2048)
    const float* cw   = (const float*)d_in[2];   // (2048,1,3)
    const float* Wout = (const float*)d_in[3];   // (2048,2048)
    float* out = (float*)d_out;                  // (2,4096,2048) fp32

    char* ws = (char*)d_ws;
    u16* hsb   = (u16*)(ws);                     //  33,554,432 B
    u16* Winb  = (u16*)(ws +  33554432);         //  25,165,824 B
    u16* Woutb = (u16*)(ws +  58720256);         //   8,388,608 B
    u16* bcx   = (u16*)(ws +  67108864);         // 100,663,296 B
    u16* yb    = (u16*)(ws + 167772160);         //  33,554,432 B  (end 201,326,592)

    cvt_all<<<32768, 256, 0, stream>>>(hs, Win, Wout, hsb, Winb, Woutb);

    // BCx = hs @ Win^T : M=8192, N=6144, K=2048  (grid 24x32 = 768 blocks)
    gemm_bt8<true ><<<dim3(24, 32), 512, 0, stream>>>(hsb, Winb, bcx, 8192, 6144, 2048);

    conv_fuse<<<8192, 256, 0, stream>>>(bcx, cw, yb);

    // out = y @ Wout^T : M=8192, N=2048, K=2048  (grid 8x32 = 256 blocks)
    gemm_bt8<false><<<dim3(8, 32), 512, 0, stream>>>(yb, Woutb, out, 8192, 2048, 2048);
}

// Round 5
// 437.382 us; speedup vs baseline: 4.8231x; 4.8231x over previous
//
#include <hip/hip_runtime.h>
#include <hip/hip_bf16.h>

typedef unsigned short u16;
typedef __attribute__((ext_vector_type(8))) short bf16x8;    // 8 bf16 in 4 VGPRs
typedef __attribute__((ext_vector_type(16))) float f32x16;

static __device__ __forceinline__ u16 f2bf(float f) {
    unsigned u = __float_as_uint(f);
    unsigned r = (u + 0x7fffu + ((u >> 16) & 1u)) >> 16;   // RNE
    return (u16)r;
}
static __device__ __forceinline__ float bf2f(u16 u) {
    return __uint_as_float(((unsigned)u) << 16);
}

static __device__ __forceinline__ void async_copy16(const void* gptr, void* lptr) {
    __builtin_amdgcn_global_load_lds(
        (const __attribute__((address_space(1))) void*)gptr,
        (__attribute__((address_space(3))) void*)lptr, 16, 0, 0);
}

// ---------------------------------------------------------------------------
// fp32 -> bf16 for all three inputs in ONE launch.
// ---------------------------------------------------------------------------
__global__ __launch_bounds__(256)
void cvt_all(const float* __restrict__ a, const float* __restrict__ b,
             const float* __restrict__ c,
             u16* __restrict__ oa, u16* __restrict__ ob, u16* __restrict__ oc) {
    int blk = blockIdx.x;
    const float* src; u16* dst; long base;
    if (blk < 16384)      { src = a; dst = oa; base = blk; }
    else if (blk < 28672) { src = b; dst = ob; base = blk - 16384; }
    else                  { src = c; dst = oc; base = blk - 28672; }
    long i = (base * 256 + threadIdx.x) * 4;
    float4 f = *(const float4*)(src + i);
    u16 o[4] = { f2bf(f.x), f2bf(f.y), f2bf(f.z), f2bf(f.w) };
    *(uint2*)(dst + i) = *(const uint2*)o;
}

// ---------------------------------------------------------------------------
// C[m,n] = sum_k A[m,k] * B[n,k]   (row-major, K contiguous — "BT" gemm)
//
// 256x256 tile, BK=64, 512 threads = 8 waves (2M x 4N), wave tile 128x64 as
// 4x2 of mfma_f32_32x32x16_bf16.
//
// R5 = R4's one-phase-ahead pipeline with the staging RACE FIXED. R4's bug:
// STAGE halves are ROW-halves (phys rows 0-63 / 64-127, all K cols) while
// fragment reads take K-column halves across ALL 128 rows -> every read
// needs BOTH row-half copies of its region landed; R4's spread-out stage
// order let ph8's cross-buffer read race its own phase's stage. NaN.
//
// Fixed calendar: stages front-loaded as whole regions (2 copies each):
//   ph1: A0'(rh0+rh1)  ph2: B0'  ph3: A1'  ph4: B1'   ph5-8: none
// Confirmation waits (vmcnt counts 2 copies/region, queue <= 8, never 0):
//   end-ph1: vmcnt(2) confirms prev-tile B1  (read ph2 body)
//   end-ph7: vmcnt(4) confirms A0',B0'       (read ph8 body, cross-buffer)
//   end-ph8: vmcnt(2) confirms A1'           (read ph1' body)
// Every region: staged >= 6 phases & confirmed >= 1 barrier before first
// read; WAR: stage target last read >= 4 phases (>= 2 barriers) earlier.
//
// Phase P body = [ds_reads for MFMA(P+1) | stages | (vmcnt) | BAR |
//                 lgkmcnt(R_P = this body's read count) | setprio MFMA x4].
// MFMA order (00h0)(10h0)(11h1... see TILE) — every consecutive pair shares
// one operand; 2 A-slots + 2 B-slots rotate, all live ranges disjoint
// (slot-content trace audited per-phase).
//
// LDS: per buf (32768 u16): A-Mq at q*8192, B-Nq at 16384+q*8192; region =
// 128 phys rows x 64 u16 (128B stride); 16B slot s = kc ^ (p&7). Swizzle
// pre-applied on GLOBAL source (global_load_lds needs linear lane*16B
// dests); reads un-swizzle with the same XOR.
// M,N mult of 256, K mult of 128, gridDim.x mult of 8, K/64 even.
// ---------------------------------------------------------------------------
template<bool BF16_OUT>
__global__ __launch_bounds__(512, 2)
void gemm_bt8(const u16* __restrict__ A, const u16* __restrict__ B,
              void* __restrict__ Cout, int M, int N, int K) {
    __shared__ __align__(16) u16 lds[65536];   // 128 KiB = 2 bufs x 64 KB

    const int t    = threadIdx.x;              // 0..511
    const int lane = t & 63;
    const int wm   = (t >> 6) >> 2;            // 0..1
    const int wn   = (t >> 6) & 3;             // 0..3
    const int l32  = lane & 31;
    const int hi   = lane >> 5;                // 0..1

    // XCD-aware panel remap (bijective since gridDim.x % 8 == 0)
    const int id   = blockIdx.y * gridDim.x + blockIdx.x;
    const int cpx  = gridDim.x >> 3;
    const int bx   = (id & 7) * cpx + ((id >> 3) % cpx);
    const int by   = (id >> 3) / cpx;
    const long rowA = (long)by * 256;
    const long rowB = (long)bx * 256;

    // ---- staging sources (pre-swizzled global addresses) ----
    // copy of row-half hh of region q: phys row p = hh*64 + (t>>3),
    // slot = t&7, logical chunk kc = slot ^ (p&7)  [(p&7)==((t>>3)&7)]
    const int tr  = t >> 3;                    // 0..63
    const int kcs = ((t & 7) ^ (tr & 7)) * 8;
    const u16* A0s = A + (rowA + tr) * (long)K + kcs;
    const u16* B0s = B + (rowB + (tr >> 5) * 64 + (tr & 31)) * (long)K + kcs;
    const long dK128 = 128 * (long)K;          // row-half hh=1: +128 rows/cols
    const long aQ = 64 * (long)K;              // A region q=1: +64 rows
    const long bQ = 32 * (long)K;              // B region q=1: +32 cols
    const int t8 = t * 8;

    auto STAGE_A = [&](int bufo, int q, int hh, int kk) {
        const u16* s = A0s + (q ? aQ : 0) + (hh ? dK128 : 0) + kk;
        async_copy16(s, lds + bufo + q * 8192 + hh * 4096 + t8);
    };
    auto STAGE_B = [&](int bufo, int q, int hh, int kk) {
        const u16* s = B0s + (q ? bQ : 0) + (hh ? dK128 : 0) + kk;
        async_copy16(s, lds + bufo + 16384 + q * 8192 + hh * 4096 + t8);
    };

    // ---- fragment read offsets (u16 units) ----
    // read addr = bufo + region + p*64 + ((kc ^ (p&7))*8), kc = ks*2+hi;
    // (kc^(p&7))*8 == (ks*16 + hi*8) ^ ((lane&7)*8)
    const int xo   = (lane & 7) * 8;
    const int hi8  = hi * 8;
    const int aRow = (wm * 64 + l32) * 64;     // + m*2048
    const int bRow = (wn * 32 + l32) * 64;
    const int cof[4] = { (0 * 16 + hi8) ^ xo, (1 * 16 + hi8) ^ xo,
                         (2 * 16 + hi8) ^ xo, (3 * 16 + hi8) ^ xo };

    bf16x8 A0f[2][2], A1f[2][2], B0f[2], B1f[2];
    f32x16 acc[4][2] = {};

    auto RD_A = [&](bf16x8 (&s)[2][2], int bufo, int q, int hK) {
#pragma unroll
        for (int m = 0; m < 2; m++)
#pragma unroll
            for (int ksl = 0; ksl < 2; ksl++)
                s[m][ksl] = *(const bf16x8*)(
                    lds + bufo + q * 8192 + aRow + m * 2048 + cof[hK * 2 + ksl]);
    };
    auto RD_B = [&](bf16x8 (&s)[2], int bufo, int q, int hK) {
#pragma unroll
        for (int ksl = 0; ksl < 2; ksl++)
            s[ksl] = *(const bf16x8*)(
                lds + bufo + 16384 + q * 8192 + bRow + cof[hK * 2 + ksl]);
    };
    auto MF = [&](bf16x8 (&AS)[2][2], bf16x8 (&BS)[2], int MQ, int NQ) {
        __builtin_amdgcn_s_setprio(1);
#pragma unroll
        for (int ksl = 0; ksl < 2; ksl++)
#pragma unroll
            for (int m = 0; m < 2; m++)
                acc[MQ * 2 + m][NQ] = __builtin_amdgcn_mfma_f32_32x32x16_bf16(
                    AS[m][ksl], BS[ksl], acc[MQ * 2 + m][NQ], 0, 0, 0);
        __builtin_amdgcn_s_setprio(0);
    };

#define BAR()   __builtin_amdgcn_s_barrier()
#define SB()    __builtin_amdgcn_sched_barrier(0)
#define LGKM(n) asm volatile("s_waitcnt lgkmcnt(" #n ")" ::: "memory")
#define VM(n)   asm volatile("s_waitcnt vmcnt(" #n ")" ::: "memory")

    // one K-tile (8 phases): compute tile in BC, stage next tile into BN.
    // Reads in body P feed MFMA(P+1); lgkm count = body P's own read count.
#define TILE(BC, BN, KK)                                                     \
    /*ph1*/ RD_A(A1f, BC, 1, 0);                                             \
            STAGE_A(BN, 0, 0, KK); STAGE_A(BN, 0, 1, KK);                    \
            VM(2); BAR(); LGKM(4); SB();  MF(A0f, B0f, 0, 0);                \
    /*ph2*/ RD_B(B1f, BC, 1, 0);                                             \
            STAGE_B(BN, 0, 0, KK); STAGE_B(BN, 0, 1, KK);                    \
            BAR(); LGKM(2); SB();  MF(A1f, B0f, 1, 0);                       \
    /*ph3*/ STAGE_A(BN, 1, 0, KK); STAGE_A(BN, 1, 1, KK);                    \
            BAR(); LGKM(0); SB();  MF(A1f, B1f, 1, 1);                       \
    /*ph4*/ RD_A(A1f, BC, 0, 1); RD_B(B0f, BC, 1, 1);                        \
            STAGE_B(BN, 1, 0, KK); STAGE_B(BN, 1, 1, KK);                    \
            BAR(); LGKM(6); SB();  MF(A0f, B1f, 0, 1);                       \
    /*ph5*/ RD_A(A0f, BC, 1, 1);                                             \
            BAR(); LGKM(4); SB();  MF(A1f, B0f, 0, 1);                       \
    /*ph6*/ RD_B(B1f, BC, 0, 1);                                             \
            BAR(); LGKM(2); SB();  MF(A0f, B0f, 1, 1);                       \
    /*ph7*/ VM(4); BAR(); LGKM(0); SB();  MF(A0f, B1f, 1, 0);                \
    /*ph8*/ RD_A(A0f, BN, 0, 0); RD_B(B0f, BN, 0, 0);                        \
            VM(2); BAR(); LGKM(6); SB();  MF(A1f, B1f, 0, 0);

    // ---- prologue: stage ALL of tile0 -> buf0; preload A0f/B0f ----
    STAGE_A(0, 0, 0, 0);  STAGE_A(0, 0, 1, 0);
    STAGE_B(0, 0, 0, 0);  STAGE_B(0, 0, 1, 0);
    STAGE_A(0, 1, 0, 0);  STAGE_A(0, 1, 1, 0);
    STAGE_B(0, 1, 0, 0);  STAGE_B(0, 1, 1, 0);
    asm volatile("s_waitcnt vmcnt(0)" ::: "memory");
    BAR();
    RD_A(A0f, 0, 0, 0);   RD_B(B0f, 0, 0, 0);

    const int NT = K >> 6;                     // K/64 tiles, even
#pragma unroll 1
    for (int i = 0; i < NT; i += 2) {
        int k1 = (i + 1) << 6;                               // tile i+1 src
        int k2 = (i + 2 < NT) ? (i + 2) << 6 : 0;            // tail: junk,
        TILE(0, 32768, k1);                                  //  never used
        TILE(32768, 0, k2);
    }
    // drain in-flight LDS-targeted loads / reads before LDS dealloc
    asm volatile("s_waitcnt vmcnt(0) lgkmcnt(0)" ::: "memory");

#undef TILE
#undef VM
#undef LGKM
#undef SB
#undef BAR

    // ---- epilogue: 32x32 C/D layout col=lane&31, row=(r&3)+8*(r>>2)+4*hi ----
#pragma unroll
    for (int mi = 0; mi < 4; mi++) {
#pragma unroll
        for (int nj = 0; nj < 2; nj++) {
#pragma unroll
            for (int r = 0; r < 16; r++) {
                int rowt = (r & 3) + 8 * (r >> 2) + 4 * hi;
                long m = rowA + wm * 128 + mi * 32 + rowt;
                long n = rowB + wn * 64 + nj * 32 + l32;
                float v = acc[mi][nj][r];
                if (BF16_OUT) ((u16*)Cout)[m * N + n] = f2bf(v);
                else          ((float*)Cout)[m * N + n] = v;
            }
        }
    }
}

// ---------------------------------------------------------------------------
// Fused Bx-product + depthwise causal conv(L=3) + C-gate.
// BCx: (8192, 6144) bf16 rows = [B(0:2048) | C(2048:4096) | x(4096:6144)]
// y[s,h] = C[s,h] * ( w[h,0]*Bx[s-2,h] + w[h,1]*Bx[s-1,h] + w[h,2]*Bx[s,h] )
// batch boundary: s resets every 4096 rows (zero left-pad per batch)
// ---------------------------------------------------------------------------
union U16x8 { uint4 v; u16 u[8]; };

__global__ __launch_bounds__(256)
void conv_fuse(const u16* __restrict__ BCx, const float* __restrict__ cw,
               u16* __restrict__ y) {
    const int row = blockIdx.x;            // 0..8191
    const int h0  = threadIdx.x * 8;       // 256*8 = 2048
    const int sl  = row & 4095;
    const u16* r0 = BCx + (long)row * 6144;

    U16x8 B0, X0, C0, B1, X1, B2, X2;
    B0.v = *(const uint4*)(r0 + h0);
    C0.v = *(const uint4*)(r0 + 2048 + h0);
    X0.v = *(const uint4*)(r0 + 4096 + h0);
    if (sl >= 1) {
        B1.v = *(const uint4*)(r0 - 6144 + h0);
        X1.v = *(const uint4*)(r0 - 6144 + 4096 + h0);
    } else { B1.v = make_uint4(0,0,0,0); X1.v = make_uint4(0,0,0,0); }
    if (sl >= 2) {
        B2.v = *(const uint4*)(r0 - 12288 + h0);
        X2.v = *(const uint4*)(r0 - 12288 + 4096 + h0);
    } else { B2.v = make_uint4(0,0,0,0); X2.v = make_uint4(0,0,0,0); }

    U16x8 o;
#pragma unroll
    for (int i = 0; i < 8; i++) {
        int h = h0 + i;
        float bx0 = bf2f(B0.u[i]) * bf2f(X0.u[i]);   // tap l=2 (current)
        float bx1 = bf2f(B1.u[i]) * bf2f(X1.u[i]);   // tap l=1 (s-1)
        float bx2 = bf2f(B2.u[i]) * bf2f(X2.u[i]);   // tap l=0 (s-2)
        float v = cw[h*3+2] * bx0 + cw[h*3+1] * bx1 + cw[h*3] * bx2;
        o.u[i] = f2bf(v * bf2f(C0.u[i]));
    }
    *(uint4*)(y + (long)row * 2048 + h0) = o.v;
}

// ---------------------------------------------------------------------------
extern "C" void kernel_launch(void* const* d_in, const int* in_sizes, int n_in,
                              void* d_out, int out_size, void* d_ws, size_t ws_size,
                              hipStream_t stream) {
    const float* hs   = (const float*)d_in[0];   // (2,4096,2048)
    const float* Win  = (const float*)d_in[1];   // (6144,2048)
    const float* cw   = (const float*)d_in[2];   // (2048,1,3)
    const float* Wout = (const float*)d_in[3];   // (2048,2048)
    float* out = (float*)d_out;                  // (2,4096,2048) fp32

    char* ws = (char*)d_ws;
    u16* hsb   = (u16*)(ws);                     //  33,554,432 B
    u16* Winb  = (u16*)(ws +  33554432);         //  25,165,824 B
    u16* Woutb = (u16*)(ws +  58720256);         //   8,388,608 B
    u16* bcx   = (u16*)(ws +  67108864);         // 100,663,296 B
    u16* yb    = (u16*)(ws + 167772160);         //  33,554,432 B  (end 201,326,592)

    cvt_all<<<32768, 256, 0, stream>>>(hs, Win, Wout, hsb, Winb, Woutb);

    // BCx = hs @ Win^T : M=8192, N=6144, K=2048  (grid 24x32 = 768 blocks)
    gemm_bt8<true ><<<dim3(24, 32), 512, 0, stream>>>(hsb, Winb, bcx, 8192, 6144, 2048);

    conv_fuse<<<8192, 256, 0, stream>>>(bcx, cw, yb);

    // out = y @ Wout^T : M=8192, N=2048, K=2048  (grid 8x32 = 256 blocks)
    gemm_bt8<false><<<dim3(8, 32), 512, 0, stream>>>(yb, Woutb, out, 8192, 2048, 2048);
}

// Round 6
// 432.885 us; speedup vs baseline: 4.8732x; 1.0104x over previous
//
#include <hip/hip_runtime.h>
#include <hip/hip_bf16.h>

typedef unsigned short u16;
typedef __attribute__((ext_vector_type(8))) short bf16x8;    // 8 bf16 in 4 VGPRs
typedef __attribute__((ext_vector_type(4))) float f32x4;

static __device__ __forceinline__ u16 f2bf(float f) {
    unsigned u = __float_as_uint(f);
    unsigned r = (u + 0x7fffu + ((u >> 16) & 1u)) >> 16;   // RNE
    return (u16)r;
}
static __device__ __forceinline__ float bf2f(u16 u) {
    return __uint_as_float(((unsigned)u) << 16);
}

static __device__ __forceinline__ void async_copy16(const void* gptr, void* lptr) {
    __builtin_amdgcn_global_load_lds(
        (const __attribute__((address_space(1))) void*)gptr,
        (__attribute__((address_space(3))) void*)lptr, 16, 0, 0);
}

// ---------------------------------------------------------------------------
// fp32 -> bf16 for all three inputs in ONE launch.
// ---------------------------------------------------------------------------
__global__ __launch_bounds__(256)
void cvt_all(const float* __restrict__ a, const float* __restrict__ b,
             const float* __restrict__ c,
             u16* __restrict__ oa, u16* __restrict__ ob, u16* __restrict__ oc) {
    int blk = blockIdx.x;
    const float* src; u16* dst; long base;
    if (blk < 16384)      { src = a; dst = oa; base = blk; }
    else if (blk < 28672) { src = b; dst = ob; base = blk - 16384; }
    else                  { src = c; dst = oc; base = blk - 28672; }
    long i = (base * 256 + threadIdx.x) * 4;
    float4 f = *(const float4*)(src + i);
    u16 o[4] = { f2bf(f.x), f2bf(f.y), f2bf(f.z), f2bf(f.w) };
    *(uint2*)(dst + i) = *(const uint2*)o;
}

// ---------------------------------------------------------------------------
// C[m,n] = sum_k A[m,k] * B[n,k]   (row-major, K contiguous — "BT" gemm)
//
// 256x256 tile, BK=64, 512 threads = 8 waves (2M x 4N), wave tile 128x64 as
// 8x4 frags of mfma_f32_16x16x32_bf16 (16-row fragment reads: measured ZERO
// bank conflicts in R1; every 32-row variant measured 1.9e7).
//
// R6: 4 phases per K-tile, ONE s_barrier per phase (R1/R5 had 2x barriers;
// phase arithmetic showed ~400cy/phase of sync overhead dominates). Phase =
// C-quadrant (Mq,Nq) x K=64 = 16 MFMA, split in two 8-MFMA halves by a
// COUNTED mid-wait so the first half starts after 8 read-services not 12:
//   body: [reads: B(4) | A-m01(4) | SB | A-m23(4)] [1 region staged]
//         [vmcnt @ph1(2)/ph4(4)] LGKM(4) SB 8xMFMA LGKM(0) SB 8xMFMA BAR
// Quadrant order (M0N0)(M0N1)(M1N1)(M1N0); B dbuf'd (ba/bb), A single set.
//
// Hazard calendar (audited, all hard-ordered):
//   stages tile T: ph1 A0' ph2 B0' ph3 A1' ph4 B1' (tile T+1 -> other buf)
//   vmcnt(4)@ph4 retires A0',B0' (read ph1' after BAR) — oldest 4 of 8;
//   vmcnt(2)@ph1 retires A1,B1 (staged prev ph3/ph4; read ph2/ph3 after BAR);
//   WAR: every stage target last read >= 3 phases (>= 3 barriers) earlier;
//   1 barrier/phase bounds drift < 1 phase; all read/stage pairs separated
//   by >= 1 barrier AFTER the staging wave's own vmcnt retire.
//   lgkm counted per phase's own reads only (0 outstanding at phase entry);
//   read groups ordered via sched_barrier so lgkm(4) retires the right 8.
//
// LDS (2 dbufs x 32768 u16): A-Mq at Mq*8192 (256 row-slots x 64 u16),
// B-Nq at 16384+Nq*8192; 16B slot s = kc ^ (rowslot&7). Swizzle pre-applied
// on the GLOBAL source at staging (global_load_lds needs linear lane*16B
// dests); fragment reads un-swizzle with the same XOR. (R1-verbatim.)
// M,N mult of 256, K mult of 128, gridDim.x mult of 8.
// ---------------------------------------------------------------------------
template<bool BF16_OUT>
__global__ __launch_bounds__(512, 2)
void gemm_bt8(const u16* __restrict__ A, const u16* __restrict__ B,
              void* __restrict__ Cout, int M, int N, int K) {
    __shared__ __align__(16) u16 lds[65536];   // 128 KiB

    const int t    = threadIdx.x;              // 0..511
    const int lane = t & 63;
    const int wm   = (t >> 6) >> 2;            // 0..1
    const int wn   = (t >> 6) & 3;             // 0..3
    const int l15  = lane & 15;
    const int hi   = lane >> 4;                // 0..3
    const int l7   = lane & 7;

    // XCD-aware panel remap (bijective since gridDim.x % 8 == 0)
    const int id   = blockIdx.y * gridDim.x + blockIdx.x;
    const int cpx  = gridDim.x >> 3;
    const int bx   = (id & 7) * cpx + ((id >> 3) % cpx);
    const int by   = (id >> 3) / cpx;
    const long rowA = (long)by * 256;
    const long rowB = (long)bx * 256;

    // ---- staging sources (pre-swizzled global addresses, R1-verbatim) ----
    const int pl0 = t >> 3;                               // 0..63
    const int slotcol = ((t & 7) ^ (pl0 & 7)) * 8;
    const u16* Asrc[2][2]; const u16* Bsrc[2][2];
#pragma unroll
    for (int h = 0; h < 2; h++) {
        int gA0 = h * 64 + pl0;
        int gA1 = 128 + h * 64 + pl0;
        Asrc[h][0] = A + (rowA + gA0) * (long)K + slotcol;
        Asrc[h][1] = A + (rowA + gA1) * (long)K + slotcol;
        int nB0 = (pl0 >> 5) * 64 + h * 32 + (pl0 & 31);
        Bsrc[h][0] = B + (rowB + nB0) * (long)K + slotcol;
        Bsrc[h][1] = B + (rowB + nB0 + 128) * (long)K + slotcol;
    }
    const int t8 = t * 8;

    auto STAGE_A = [&](int bufo, int h, int kk) {
        u16* d = lds + bufo + h * 8192 + t8;
        async_copy16(Asrc[h][0] + kk, d);
        async_copy16(Asrc[h][1] + kk, d + 4096);
    };
    auto STAGE_B = [&](int bufo, int h, int kk) {
        u16* d = lds + bufo + 16384 + h * 8192 + t8;
        async_copy16(Bsrc[h][0] + kk, d);
        async_copy16(Bsrc[h][1] + kk, d + 4096);
    };

    // ---- fragment read offsets (u16 units, R1-verbatim) ----
    const int aBase = wm * 4096 + l15 * 64;
    const int bBase = 16384 + wn * 2048 + l15 * 64;
    const int sOff0 = (hi ^ l7) * 8;            // ks=0
    const int sOff1 = ((4 + hi) ^ l7) * 8;      // ks=1

    bf16x8 af[4][2], ba[2][2], bb[2][2];
    f32x4 acc[8][4] = {};

    auto LOAD_A2 = [&](int bufo, int Mq, int mb) {   // af[mb], af[mb+1]
        const u16* p = lds + bufo + Mq * 8192 + aBase + mb * 1024;
        af[mb][0]     = *(const bf16x8*)(p + sOff0);
        af[mb][1]     = *(const bf16x8*)(p + sOff1);
        af[mb + 1][0] = *(const bf16x8*)(p + 1024 + sOff0);
        af[mb + 1][1] = *(const bf16x8*)(p + 1024 + sOff1);
    };
    auto LOAD_B = [&](bf16x8 (&bg)[2][2], int bufo, int Nq) {
        const u16* p = lds + bufo + Nq * 8192 + bBase;
        bg[0][0] = *(const bf16x8*)(p + sOff0);
        bg[0][1] = *(const bf16x8*)(p + sOff1);
        bg[1][0] = *(const bf16x8*)(p + 1024 + sOff0);
        bg[1][1] = *(const bf16x8*)(p + 1024 + sOff1);
    };
    auto MFMA_H = [&](int Mq, int Nq, int mb, bf16x8 (&bg)[2][2]) {
        __builtin_amdgcn_s_setprio(1);
#pragma unroll
        for (int ks = 0; ks < 2; ks++)
#pragma unroll
            for (int m = mb; m < mb + 2; m++)
#pragma unroll
                for (int n = 0; n < 2; n++)
                    acc[Mq * 4 + m][Nq * 2 + n] =
                        __builtin_amdgcn_mfma_f32_16x16x32_bf16(
                            af[m][ks], bg[n][ks], acc[Mq * 4 + m][Nq * 2 + n],
                            0, 0, 0);
        __builtin_amdgcn_s_setprio(0);
    };

#define BAR()   __builtin_amdgcn_s_barrier()
#define SB()    __builtin_amdgcn_sched_barrier(0)
#define LGKM(n) do { asm volatile("s_waitcnt lgkmcnt(" #n ")" ::: "memory"); \
                     __builtin_amdgcn_sched_barrier(0); } while (0)
#define VM(n)   asm volatile("s_waitcnt vmcnt(" #n ")" ::: "memory")

    // one K-tile = 4 phases, 1 barrier each; reads from BC, stages -> BN
#define TILE(BC, BN, KK)                                                     \
    /*ph1 Q(M0N0)*/                                                          \
    LOAD_B(ba, BC, 0); LOAD_A2(BC, 0, 0); SB(); LOAD_A2(BC, 0, 2);           \
    STAGE_A(BN, 0, KK); VM(2);                                               \
    LGKM(4); MFMA_H(0, 0, 0, ba); LGKM(0); MFMA_H(0, 0, 2, ba); BAR();       \
    /*ph2 Q(M0N1)*/                                                          \
    LOAD_B(bb, BC, 1);                                                       \
    STAGE_B(BN, 0, KK);                                                      \
    LGKM(0); MFMA_H(0, 1, 0, bb); MFMA_H(0, 1, 2, bb); BAR();                \
    /*ph3 Q(M1N1)*/                                                          \
    LOAD_A2(BC, 1, 0); SB(); LOAD_A2(BC, 1, 2);                              \
    STAGE_A(BN, 1, KK);                                                      \
    LGKM(4); MFMA_H(1, 1, 0, bb); LGKM(0); MFMA_H(1, 1, 2, bb); BAR();       \
    /*ph4 Q(M1N0)*/                                                          \
    STAGE_B(BN, 1, KK); VM(4);                                               \
    MFMA_H(1, 0, 0, ba); MFMA_H(1, 0, 2, ba); BAR();

    // ---- prologue: stage ALL of tile0 -> buf0 ----
    STAGE_A(0, 0, 0);  STAGE_B(0, 0, 0);
    STAGE_A(0, 1, 0);  STAGE_B(0, 1, 0);
    asm volatile("s_waitcnt vmcnt(0)" ::: "memory");
    BAR();

    const int NT = K >> 6;                     // K/64 tiles, even
#pragma unroll 1
    for (int i = 0; i < NT; i += 2) {
        int k1 = (i + 1) << 6;                               // tile i+1 src
        int k2 = (i + 2 < NT) ? (i + 2) << 6 : 0;            // tail: junk,
        TILE(0, 32768, k1);                                  //  never read
        TILE(32768, 0, k2);
    }
    // drain in-flight LDS-targeted loads / reads before LDS dealloc
    asm volatile("s_waitcnt vmcnt(0) lgkmcnt(0)" ::: "memory");

#undef TILE
#undef VM
#undef LGKM
#undef SB
#undef BAR

    // ---- epilogue: 16x16 C/D layout col=lane&15, row=(lane>>4)*4+r ----
    const long crowBase = rowA + wm * 128 + hi * 4;
    const long ccolBase = rowB + wn * 64 + l15;
#pragma unroll
    for (int mi = 0; mi < 8; mi++) {
#pragma unroll
        for (int nj = 0; nj < 4; nj++) {
            long base = (crowBase + mi * 16) * N + ccolBase + nj * 16;
#pragma unroll
            for (int r = 0; r < 4; r++) {
                float v = acc[mi][nj][r];
                long idx = base + (long)r * N;
                if (BF16_OUT) ((u16*)Cout)[idx] = f2bf(v);
                else          ((float*)Cout)[idx] = v;
            }
        }
    }
}

// ---------------------------------------------------------------------------
// Fused Bx-product + depthwise causal conv(L=3) + C-gate.
// BCx: (8192, 6144) bf16 rows = [B(0:2048) | C(2048:4096) | x(4096:6144)]
// y[s,h] = C[s,h] * ( w[h,0]*Bx[s-2,h] + w[h,1]*Bx[s-1,h] + w[h,2]*Bx[s,h] )
// batch boundary: s resets every 4096 rows (zero left-pad per batch)
// ---------------------------------------------------------------------------
union U16x8 { uint4 v; u16 u[8]; };

__global__ __launch_bounds__(256)
void conv_fuse(const u16* __restrict__ BCx, const float* __restrict__ cw,
               u16* __restrict__ y) {
    const int row = blockIdx.x;            // 0..8191
    const int h0  = threadIdx.x * 8;       // 256*8 = 2048
    const int sl  = row & 4095;
    const u16* r0 = BCx + (long)row * 6144;

    U16x8 B0, X0, C0, B1, X1, B2, X2;
    B0.v = *(const uint4*)(r0 + h0);
    C0.v = *(const uint4*)(r0 + 2048 + h0);
    X0.v = *(const uint4*)(r0 + 4096 + h0);
    if (sl >= 1) {
        B1.v = *(const uint4*)(r0 - 6144 + h0);
        X1.v = *(const uint4*)(r0 - 6144 + 4096 + h0);
    } else { B1.v = make_uint4(0,0,0,0); X1.v = make_uint4(0,0,0,0); }
    if (sl >= 2) {
        B2.v = *(const uint4*)(r0 - 12288 + h0);
        X2.v = *(const uint4*)(r0 - 12288 + 4096 + h0);
    } else { B2.v = make_uint4(0,0,0,0); X2.v = make_uint4(0,0,0,0); }

    U16x8 o;
#pragma unroll
    for (int i = 0; i < 8; i++) {
        int h = h0 + i;
        float bx0 = bf2f(B0.u[i]) * bf2f(X0.u[i]);   // tap l=2 (current)
        float bx1 = bf2f(B1.u[i]) * bf2f(X1.u[i]);   // tap l=1 (s-1)
        float bx2 = bf2f(B2.u[i]) * bf2f(X2.u[i]);   // tap l=0 (s-2)
        float v = cw[h*3+2] * bx0 + cw[h*3+1] * bx1 + cw[h*3] * bx2;
        o.u[i] = f2bf(v * bf2f(C0.u[i]));
    }
    *(uint4*)(y + (long)row * 2048 + h0) = o.v;
}

// ---------------------------------------------------------------------------
extern "C" void kernel_launch(void* const* d_in, const int* in_sizes, int n_in,
                              void* d_out, int out_size, void* d_ws, size_t ws_size,
                              hipStream_t stream) {
    const float* hs   = (const float*)d_in[0];   // (2,4096,2048)
    const float* Win  = (const float*)d_in[1];   // (6144,2048)
    const float* cw   = (const float*)d_in[2];   // (2048,1,3)
    const float* Wout = (const float*)d_in[3];   // (2048,2048)
    float* out = (float*)d_out;                  // (2,4096,2048) fp32

    char* ws = (char*)d_ws;
    u16* hsb   = (u16*)(ws);                     //  33,554,432 B
    u16* Winb  = (u16*)(ws +  33554432);         //  25,165,824 B
    u16* Woutb = (u16*)(ws +  58720256);         //   8,388,608 B
    u16* bcx   = (u16*)(ws +  67108864);         // 100,663,296 B
    u16* yb    = (u16*)(ws + 167772160);         //  33,554,432 B  (end 201,326,592)

    cvt_all<<<32768, 256, 0, stream>>>(hs, Win, Wout, hsb, Winb, Woutb);

    // BCx = hs @ Win^T : M=8192, N=6144, K=2048  (grid 24x32 = 768 blocks)
    gemm_bt8<true ><<<dim3(24, 32), 512, 0, stream>>>(hsb, Winb, bcx, 8192, 6144, 2048);

    conv_fuse<<<8192, 256, 0, stream>>>(bcx, cw, yb);

    // out = y @ Wout^T : M=8192, N=2048, K=2048  (grid 8x32 = 256 blocks)
    gemm_bt8<false><<<dim3(8, 32), 512, 0, stream>>>(yb, Woutb, out, 8192, 2048, 2048);
}

// Round 7
// 424.110 us; speedup vs baseline: 4.9740x; 1.0207x over previous
//
#include <hip/hip_runtime.h>
#include <hip/hip_bf16.h>

typedef unsigned short u16;
typedef __attribute__((ext_vector_type(8))) short bf16x8;    // 8 bf16 in 4 VGPRs
typedef __attribute__((ext_vector_type(4))) float f32x4;

static __device__ __forceinline__ u16 f2bf(float f) {
    unsigned u = __float_as_uint(f);
    unsigned r = (u + 0x7fffu + ((u >> 16) & 1u)) >> 16;   // RNE
    return (u16)r;
}
static __device__ __forceinline__ float bf2f(u16 u) {
    return __uint_as_float(((unsigned)u) << 16);
}

static __device__ __forceinline__ void async_copy16(const void* gptr, void* lptr) {
    __builtin_amdgcn_global_load_lds(
        (const __attribute__((address_space(1))) void*)gptr,
        (__attribute__((address_space(3))) void*)lptr, 16, 0, 0);
}

// ---------------------------------------------------------------------------
// fp32 -> bf16 for all three inputs in ONE launch.
// ---------------------------------------------------------------------------
__global__ __launch_bounds__(256)
void cvt_all(const float* __restrict__ a, const float* __restrict__ b,
             const float* __restrict__ c,
             u16* __restrict__ oa, u16* __restrict__ ob, u16* __restrict__ oc) {
    int blk = blockIdx.x;
    const float* src; u16* dst; long base;
    if (blk < 16384)      { src = a; dst = oa; base = blk; }
    else if (blk < 28672) { src = b; dst = ob; base = blk - 16384; }
    else                  { src = c; dst = oc; base = blk - 28672; }
    long i = (base * 256 + threadIdx.x) * 4;
    float4 f = *(const float4*)(src + i);
    u16 o[4] = { f2bf(f.x), f2bf(f.y), f2bf(f.z), f2bf(f.w) };
    *(uint2*)(dst + i) = *(const uint2*)o;
}

// ---------------------------------------------------------------------------
// C[m,n] = sum_k A[m,k] * B[n,k]   (row-major, K contiguous — "BT" gemm)
//
// 256x256 tile, BK=64, 512 threads = 8 waves (2M x 4N), wave tile 128x64 as
// 8x4 frags of mfma_f32_16x16x32_bf16 (16-row fragment reads = measured ZERO
// bank conflicts; 32-row variants measured 1.9e7).
//
// R7: one-phase-ahead prefetch, REGISTER-NEUTRAL (same af/ba/bb sets as R6;
// reads issued textually AFTER the MFMA that last consumes the destination
// registers -> in-order reuse, no extra sets, no spill). R6's counter model:
// 1112 cyc/phase vs 621 MFMA floor — the gap was same-phase read waits.
//   ph1 (M0N0): read bb<-B-N1(BC) pre-MFMA; LGKM(4) retires prev-ph4's 12.
//   ph2 (M0N1): LGKM(0) free; post-MFMA read af<-A-M1(BC) (8).
//   ph3 (M1N1): LGKM(0) (drained under ph2 MFMA + BAR).
//   ph4 (M1N0): LGKM(0) free; post-MFMA read ba<-B-N0, af<-A-M0 of BN (12).
// Stage calendar: ph2: A0'+B0'; ph3: B1'+A1' (this order fixes vmcnt retire
// order). Counted waits PRE-BARRIER (barrier publishes across waves):
//   VM(4)@ph3-end retires A0',B0'  -> ph4's cross-buffer reads safe
//   VM(2)@ph4-end retires B1'      -> ph1' bb read safe
//   VM(0)@ph1-end retires A1' (staged 2 phases ~2200cy ago; HBM ~900cy: free)
// WAR audit: every region overwrite >= 4 barriers after its readers'
// lgkm-drain point (drains all occur pre-barrier in the reader's phase).
//
// LDS (2 dbufs x 32768 u16): A-Mq at Mq*8192, B-Nq at 16384+Nq*8192;
// 16B slot s = kc ^ (rowslot&7). Swizzle pre-applied on the GLOBAL source
// (global_load_lds needs linear lane*16B dests); reads un-swizzle with the
// same XOR. (R1-verbatim geometry.)
// M,N mult of 256, K mult of 128, gridDim.x mult of 8.
// ---------------------------------------------------------------------------
template<bool BF16_OUT>
__global__ __launch_bounds__(512, 2)
void gemm_bt8(const u16* __restrict__ A, const u16* __restrict__ B,
              void* __restrict__ Cout, int M, int N, int K) {
    __shared__ __align__(16) u16 lds[65536];   // 128 KiB

    const int t    = threadIdx.x;              // 0..511
    const int lane = t & 63;
    const int wm   = (t >> 6) >> 2;            // 0..1
    const int wn   = (t >> 6) & 3;             // 0..3
    const int l15  = lane & 15;
    const int hi   = lane >> 4;                // 0..3
    const int l7   = lane & 7;

    // XCD-aware panel remap (bijective since gridDim.x % 8 == 0)
    const int id   = blockIdx.y * gridDim.x + blockIdx.x;
    const int cpx  = gridDim.x >> 3;
    const int bx   = (id & 7) * cpx + ((id >> 3) % cpx);
    const int by   = (id >> 3) / cpx;
    const long rowA = (long)by * 256;
    const long rowB = (long)bx * 256;

    // ---- staging sources (pre-swizzled global addresses, R1-verbatim) ----
    const int pl0 = t >> 3;                               // 0..63
    const int slotcol = ((t & 7) ^ (pl0 & 7)) * 8;
    const u16* Asrc[2][2]; const u16* Bsrc[2][2];
#pragma unroll
    for (int h = 0; h < 2; h++) {
        int gA0 = h * 64 + pl0;
        int gA1 = 128 + h * 64 + pl0;
        Asrc[h][0] = A + (rowA + gA0) * (long)K + slotcol;
        Asrc[h][1] = A + (rowA + gA1) * (long)K + slotcol;
        int nB0 = (pl0 >> 5) * 64 + h * 32 + (pl0 & 31);
        Bsrc[h][0] = B + (rowB + nB0) * (long)K + slotcol;
        Bsrc[h][1] = B + (rowB + nB0 + 128) * (long)K + slotcol;
    }
    const int t8 = t * 8;

    auto STAGE_A = [&](int bufo, int h, int kk) {
        u16* d = lds + bufo + h * 8192 + t8;
        async_copy16(Asrc[h][0] + kk, d);
        async_copy16(Asrc[h][1] + kk, d + 4096);
    };
    auto STAGE_B = [&](int bufo, int h, int kk) {
        u16* d = lds + bufo + 16384 + h * 8192 + t8;
        async_copy16(Bsrc[h][0] + kk, d);
        async_copy16(Bsrc[h][1] + kk, d + 4096);
    };

    // ---- fragment read offsets (u16 units, R1-verbatim) ----
    const int aBase = wm * 4096 + l15 * 64;
    const int bBase = 16384 + wn * 2048 + l15 * 64;
    const int sOff0 = (hi ^ l7) * 8;            // ks=0
    const int sOff1 = ((4 + hi) ^ l7) * 8;      // ks=1

    bf16x8 af[4][2], ba[2][2], bb[2][2];
    f32x4 acc[8][4] = {};

    auto LOAD_A4 = [&](int bufo, int Mq) {      // all 8 A-frag reads
        const u16* p = lds + bufo + Mq * 8192 + aBase;
#pragma unroll
        for (int m = 0; m < 4; m++) {
            af[m][0] = *(const bf16x8*)(p + m * 1024 + sOff0);
            af[m][1] = *(const bf16x8*)(p + m * 1024 + sOff1);
        }
    };
    auto LOAD_B = [&](bf16x8 (&bg)[2][2], int bufo, int Nq) {
        const u16* p = lds + bufo + Nq * 8192 + bBase;
        bg[0][0] = *(const bf16x8*)(p + sOff0);
        bg[0][1] = *(const bf16x8*)(p + sOff1);
        bg[1][0] = *(const bf16x8*)(p + 1024 + sOff0);
        bg[1][1] = *(const bf16x8*)(p + 1024 + sOff1);
    };
    auto MFMA_F = [&](int Mq, int Nq, bf16x8 (&bg)[2][2]) {
        __builtin_amdgcn_s_setprio(1);
#pragma unroll
        for (int ks = 0; ks < 2; ks++)
#pragma unroll
            for (int m = 0; m < 4; m++)
#pragma unroll
                for (int n = 0; n < 2; n++)
                    acc[Mq * 4 + m][Nq * 2 + n] =
                        __builtin_amdgcn_mfma_f32_16x16x32_bf16(
                            af[m][ks], bg[n][ks], acc[Mq * 4 + m][Nq * 2 + n],
                            0, 0, 0);
        __builtin_amdgcn_s_setprio(0);
    };

#define BAR()   __builtin_amdgcn_s_barrier()
#define SB()    __builtin_amdgcn_sched_barrier(0)
#define LGKM(n) do { asm volatile("s_waitcnt lgkmcnt(" #n ")" ::: "memory"); \
                     __builtin_amdgcn_sched_barrier(0); } while (0)
#define VM(n)   asm volatile("s_waitcnt vmcnt(" #n ")" ::: "memory")

    // one K-tile = 4 phases, 1 barrier each; compute from BC, stage -> BN
#define TILE(BC, BN, KK)                                                     \
    /*ph1 Q(M0N0): bb prefetch for ph2/ph3; drain prev-ph4's 12 reads */     \
    LOAD_B(bb, BC, 1);                                                       \
    LGKM(4); MFMA_F(0, 0, ba);                                               \
    VM(0); BAR();                                                            \
    /*ph2 Q(M0N1): stage A0',B0'; post-MFMA prefetch af<-A-M1 */             \
    STAGE_A(BN, 0, KK); STAGE_B(BN, 0, KK);                                  \
    LGKM(0); MFMA_F(0, 1, bb);                                               \
    SB(); LOAD_A4(BC, 1);                                                    \
    BAR();                                                                   \
    /*ph3 Q(M1N1): stage B1',A1' (retire order!); publish A0'B0' */          \
    STAGE_B(BN, 1, KK); STAGE_A(BN, 1, KK);                                  \
    LGKM(0); MFMA_F(1, 1, bb);                                               \
    VM(4); BAR();                                                            \
    /*ph4 Q(M1N0): post-MFMA cross-buffer prefetch ba,af; publish B1' */     \
    LGKM(0); MFMA_F(1, 0, ba);                                               \
    SB(); LOAD_B(ba, BN, 0); LOAD_A4(BN, 0);                                 \
    VM(2); BAR();

    // ---- prologue: stage ALL of tile0 -> buf0; preload af(M0), ba(N0) ----
    STAGE_A(0, 0, 0);  STAGE_B(0, 0, 0);
    STAGE_A(0, 1, 0);  STAGE_B(0, 1, 0);
    asm volatile("s_waitcnt vmcnt(0)" ::: "memory");
    BAR();
    LOAD_A4(0, 0);  LOAD_B(ba, 0, 0);          // 12 reads, mirrors ph4-post

    const int NT = K >> 6;                     // K/64 tiles, even
#pragma unroll 1
    for (int i = 0; i < NT; i += 2) {
        int k1 = (i + 1) << 6;                               // tile i+1 src
        int k2 = (i + 2 < NT) ? (i + 2) << 6 : 0;            // tail: junk,
        TILE(0, 32768, k1);                                  //  never read
        TILE(32768, 0, k2);
    }
    // drain in-flight LDS-targeted loads / reads before LDS dealloc
    asm volatile("s_waitcnt vmcnt(0) lgkmcnt(0)" ::: "memory");

#undef TILE
#undef VM
#undef LGKM
#undef SB
#undef BAR

    // ---- epilogue: 16x16 C/D layout col=lane&15, row=(lane>>4)*4+r ----
    const long crowBase = rowA + wm * 128 + hi * 4;
    const long ccolBase = rowB + wn * 64 + l15;
#pragma unroll
    for (int mi = 0; mi < 8; mi++) {
#pragma unroll
        for (int nj = 0; nj < 4; nj++) {
            long base = (crowBase + mi * 16) * N + ccolBase + nj * 16;
#pragma unroll
            for (int r = 0; r < 4; r++) {
                float v = acc[mi][nj][r];
                long idx = base + (long)r * N;
                if (BF16_OUT) ((u16*)Cout)[idx] = f2bf(v);
                else          ((float*)Cout)[idx] = v;
            }
        }
    }
}

// ---------------------------------------------------------------------------
// Fused Bx-product + depthwise causal conv(L=3) + C-gate.
// BCx: (8192, 6144) bf16 rows = [B(0:2048) | C(2048:4096) | x(4096:6144)]
// y[s,h] = C[s,h] * ( w[h,0]*Bx[s-2,h] + w[h,1]*Bx[s-1,h] + w[h,2]*Bx[s,h] )
// batch boundary: s resets every 4096 rows (zero left-pad per batch)
// ---------------------------------------------------------------------------
union U16x8 { uint4 v; u16 u[8]; };

__global__ __launch_bounds__(256)
void conv_fuse(const u16* __restrict__ BCx, const float* __restrict__ cw,
               u16* __restrict__ y) {
    const int row = blockIdx.x;            // 0..8191
    const int h0  = threadIdx.x * 8;       // 256*8 = 2048
    const int sl  = row & 4095;
    const u16* r0 = BCx + (long)row * 6144;

    U16x8 B0, X0, C0, B1, X1, B2, X2;
    B0.v = *(const uint4*)(r0 + h0);
    C0.v = *(const uint4*)(r0 + 2048 + h0);
    X0.v = *(const uint4*)(r0 + 4096 + h0);
    if (sl >= 1) {
        B1.v = *(const uint4*)(r0 - 6144 + h0);
        X1.v = *(const uint4*)(r0 - 6144 + 4096 + h0);
    } else { B1.v = make_uint4(0,0,0,0); X1.v = make_uint4(0,0,0,0); }
    if (sl >= 2) {
        B2.v = *(const uint4*)(r0 - 12288 + h0);
        X2.v = *(const uint4*)(r0 - 12288 + 4096 + h0);
    } else { B2.v = make_uint4(0,0,0,0); X2.v = make_uint4(0,0,0,0); }

    U16x8 o;
#pragma unroll
    for (int i = 0; i < 8; i++) {
        int h = h0 + i;
        float bx0 = bf2f(B0.u[i]) * bf2f(X0.u[i]);   // tap l=2 (current)
        float bx1 = bf2f(B1.u[i]) * bf2f(X1.u[i]);   // tap l=1 (s-1)
        float bx2 = bf2f(B2.u[i]) * bf2f(X2.u[i]);   // tap l=0 (s-2)
        float v = cw[h*3+2] * bx0 + cw[h*3+1] * bx1 + cw[h*3] * bx2;
        o.u[i] = f2bf(v * bf2f(C0.u[i]));
    }
    *(uint4*)(y + (long)row * 2048 + h0) = o.v;
}

// ---------------------------------------------------------------------------
extern "C" void kernel_launch(void* const* d_in, const int* in_sizes, int n_in,
                              void* d_out, int out_size, void* d_ws, size_t ws_size,
                              hipStream_t stream) {
    const float* hs   = (const float*)d_in[0];   // (2,4096,2048)
    const float* Win  = (const float*)d_in[1];   // (6144,2048)
    const float* cw   = (const float*)d_in[2];   // (2048,1,3)
    const float* Wout = (const float*)d_in[3];   // (2048,2048)
    float* out = (float*)d_out;                  // (2,4096,2048) fp32

    char* ws = (char*)d_ws;
    u16* hsb   = (u16*)(ws);                     //  33,554,432 B
    u16* Winb  = (u16*)(ws +  33554432);         //  25,165,824 B
    u16* Woutb = (u16*)(ws +  58720256);         //   8,388,608 B
    u16* bcx   = (u16*)(ws +  67108864);         // 100,663,296 B
    u16* yb    = (u16*)(ws + 167772160);         //  33,554,432 B  (end 201,326,592)

    cvt_all<<<32768, 256, 0, stream>>>(hs, Win, Wout, hsb, Winb, Woutb);

    // BCx = hs @ Win^T : M=8192, N=6144, K=2048  (grid 24x32 = 768 blocks)
    gemm_bt8<true ><<<dim3(24, 32), 512, 0, stream>>>(hsb, Winb, bcx, 8192, 6144, 2048);

    conv_fuse<<<8192, 256, 0, stream>>>(bcx, cw, yb);

    // out = y @ Wout^T : M=8192, N=2048, K=2048  (grid 8x32 = 256 blocks)
    gemm_bt8<false><<<dim3(8, 32), 512, 0, stream>>>(yb, Woutb, out, 8192, 2048, 2048);
}